// Round 4
// baseline (687.835 us; speedup 1.0000x reference)
//
#include <hip/hip_runtime.h>
#include <hip/hip_bf16.h>

// GCN layer: N=100000, E=1600000, IN=256, OUT=32, fp32.
// Bucketed-LDS pipeline, small buckets for latency hiding:
//   1) degree_kernel: cnt_out[src]++, cnt_in[dst]++, per-block bucket hist
//   2) gemm_kernel:   h = (feat * out_deg^-0.5) @ W   (R=8 x C=4 per thread)
//   3) bucket_scan:   exclusive scan of 1024 bucket counts
//   4) partition_kernel: LDS counting sort -> pairs[] grouped by dst-bucket
//      (packed u32: src[16:0] | dstlow[23:17]); coalesced segment flush
//   5) bucket_agg_kernel: 782 blocks, 16KB LDS acc[128][32] (bank=lane),
//      8 groups x unroll 8 -> ~192 outstanding loads/CU; fused epilogue
// Fallback: float-atomic aggregate if ws too small or N >= 2^17.

#define IN_F 256
#define OUT_F 32

// gemm tiling
#define G_ROWS 256
#define G_KT 32
#define G_KPAD 36

// buckets
#define BSHIFT 7
#define BNODES 128
#define NBK 1024
#define DEG_EPB 4096
#define PB_EDGES 8192

__global__ __launch_bounds__(256) void degree_kernel(
    const int* __restrict__ src, const int* __restrict__ dst,
    int* __restrict__ cnt_out, int* __restrict__ cnt_in,
    int* __restrict__ bucket_cnt, int E) {
  __shared__ int hist[NBK];
  int tid = threadIdx.x;
#pragma unroll
  for (int i = 0; i < NBK / 256; ++i) hist[tid + i * 256] = 0;
  __syncthreads();
  int base = blockIdx.x * DEG_EPB + tid * 16;
  if (base + 16 <= E) {
#pragma unroll
    for (int i = 0; i < 4; ++i) {
      int4 s4 = ((const int4*)(src + base))[i];
      int4 d4 = ((const int4*)(dst + base))[i];
      int ss[4] = {s4.x, s4.y, s4.z, s4.w};
      int dd[4] = {d4.x, d4.y, d4.z, d4.w};
#pragma unroll
      for (int k = 0; k < 4; ++k) {
        atomicAdd(cnt_out + ss[k], 1);
        atomicAdd(cnt_in + dd[k], 1);
        atomicAdd(&hist[dd[k] >> BSHIFT], 1);
      }
    }
  } else {
    for (int j = 0; j < 16; ++j) {
      int e = base + j;
      if (e < E) {
        int s = src[e], d = dst[e];
        atomicAdd(cnt_out + s, 1);
        atomicAdd(cnt_in + d, 1);
        atomicAdd(&hist[d >> BSHIFT], 1);
      }
    }
  }
  __syncthreads();
#pragma unroll
  for (int i = 0; i < NBK / 256; ++i) {
    int b = tid + i * 256;
    if (hist[b]) atomicAdd(bucket_cnt + b, hist[b]);
  }
}

// h[n][o] = sum_k feat[n][k] * out_deg[n]^-0.5 * W[k][o]
// 256 rows/block, thread = 8 rows (stride 32) x 4 cols.
__global__ __launch_bounds__(256, 2) void gemm_kernel(
    const float* __restrict__ feat, const float* __restrict__ W,
    const int* __restrict__ cnt_out, float* __restrict__ h, int N) {
  __shared__ float sW[IN_F * OUT_F];        // 32 KB
  __shared__ float sF[G_ROWS * G_KPAD];     // 36 KB
  __shared__ float sScale[G_ROWS];

  int tid = threadIdx.x;
  {
    const float4* W4 = (const float4*)W;
    float4* sW4 = (float4*)sW;
#pragma unroll
    for (int i = 0; i < 8; ++i) sW4[tid + i * 256] = W4[tid + i * 256];
  }
  int row0 = blockIdx.x * G_ROWS;
  {
    int gr = row0 + tid;
    float dg = (gr < N) ? (float)cnt_out[gr] : 1.f;
    sScale[tid] = dg < 1.f ? 1.f : rsqrtf(dg);
  }

  int tr = tid >> 3;          // 0..31
  int cg = (tid & 7) * 4;     // col group
  float acc[8][4];
#pragma unroll
  for (int i = 0; i < 8; ++i)
#pragma unroll
    for (int c = 0; c < 4; ++c) acc[i][c] = 0.f;

  for (int kt = 0; kt < IN_F; kt += G_KT) {
    __syncthreads();
    // stage 256 rows x 32 k = 2048 float4; 8 per thread; coalesced 1KB/wave
#pragma unroll
    for (int i = 0; i < 8; ++i) {
      int idx = tid + i * 256;
      int r = idx >> 3;            // 8 f4 per row
      int kk = (idx & 7) * 4;
      int gr = row0 + r;
      float4 v = {0.f, 0.f, 0.f, 0.f};
      if (gr < N) {
        float s = sScale[r];
        v = *(const float4*)(feat + (size_t)gr * IN_F + kt + kk);
        v.x *= s; v.y *= s; v.z *= s; v.w *= s;
      }
      *(float4*)(sF + r * G_KPAD + kk) = v;
    }
    __syncthreads();

#pragma unroll
    for (int k4 = 0; k4 < G_KT; k4 += 4) {
      float4 a[8];
#pragma unroll
      for (int i = 0; i < 8; ++i)
        a[i] = *(const float4*)(sF + (tr + 32 * i) * G_KPAD + k4);
#pragma unroll
      for (int j = 0; j < 4; ++j) {
        float4 w = *(const float4*)(sW + (kt + k4 + j) * OUT_F + cg);
#pragma unroll
        for (int i = 0; i < 8; ++i) {
          float aj = (j == 0) ? a[i].x : (j == 1) ? a[i].y : (j == 2) ? a[i].z : a[i].w;
          acc[i][0] += aj * w.x;
          acc[i][1] += aj * w.y;
          acc[i][2] += aj * w.z;
          acc[i][3] += aj * w.w;
        }
      }
    }
  }

#pragma unroll
  for (int i = 0; i < 8; ++i) {
    int g = row0 + tr + 32 * i;
    if (g < N) {
      float4 o = {acc[i][0], acc[i][1], acc[i][2], acc[i][3]};
      *(float4*)(h + (size_t)g * OUT_F + cg) = o;
    }
  }
}

__global__ __launch_bounds__(1024) void bucket_scan_kernel(
    const int* __restrict__ bucket_cnt, int* __restrict__ bucket_base,
    int* __restrict__ bucket_cursor) {
  __shared__ int wsum[16];
  int tid = threadIdx.x;
  int v = bucket_cnt[tid];
  int x = v;
#pragma unroll
  for (int d = 1; d < 64; d <<= 1) {
    int y = __shfl_up(x, d, 64);
    if ((tid & 63) >= d) x += y;
  }
  if ((tid & 63) == 63) wsum[tid >> 6] = x;
  __syncthreads();
  int off = 0;
#pragma unroll
  for (int w = 0; w < 16; ++w)
    if (w < (tid >> 6)) off += wsum[w];
  int excl = off + x - v;
  bucket_base[tid] = excl;
  bucket_cursor[tid] = excl;
}

__global__ __launch_bounds__(1024) void partition_kernel(
    const int* __restrict__ src, const int* __restrict__ dst,
    int* __restrict__ bucket_cursor, unsigned* __restrict__ pairs, int E) {
  __shared__ unsigned sbuf[PB_EDGES];   // 32 KB
  __shared__ int hist[NBK];             // 4 KB
  __shared__ int lbase[NBK + 1];
  __shared__ int gbase[NBK];
  __shared__ int wsum[16];

  int tid = threadIdx.x;
  hist[tid] = 0;
  __syncthreads();

  int e0 = blockIdx.x * PB_EDGES + tid * 8;
  int myb[8], myslot[8];
  unsigned mypk[8];
  if (e0 + 8 <= E) {
    int4 s0 = ((const int4*)(src + e0))[0];
    int4 s1 = ((const int4*)(src + e0))[1];
    int4 d0 = ((const int4*)(dst + e0))[0];
    int4 d1 = ((const int4*)(dst + e0))[1];
    int ss[8] = {s0.x, s0.y, s0.z, s0.w, s1.x, s1.y, s1.z, s1.w};
    int dd[8] = {d0.x, d0.y, d0.z, d0.w, d1.x, d1.y, d1.z, d1.w};
#pragma unroll
    for (int j = 0; j < 8; ++j) {
      int b = dd[j] >> BSHIFT;
      myb[j] = b;
      mypk[j] = (unsigned)ss[j] | ((unsigned)(dd[j] & (BNODES - 1)) << 17);
      myslot[j] = atomicAdd(&hist[b], 1);
    }
  } else {
#pragma unroll
    for (int j = 0; j < 8; ++j) {
      int e = e0 + j;
      if (e < E) {
        int s = src[e], d = dst[e];
        int b = d >> BSHIFT;
        myb[j] = b;
        mypk[j] = (unsigned)s | ((unsigned)(d & (BNODES - 1)) << 17);
        myslot[j] = atomicAdd(&hist[b], 1);
      } else {
        myb[j] = -1;
      }
    }
  }
  __syncthreads();

  // exclusive scan of hist[0..1023]
  {
    int v = hist[tid];
    int x = v;
#pragma unroll
    for (int d = 1; d < 64; d <<= 1) {
      int y = __shfl_up(x, d, 64);
      if ((tid & 63) >= d) x += y;
    }
    if ((tid & 63) == 63) wsum[tid >> 6] = x;
    __syncthreads();
    int off = 0;
#pragma unroll
    for (int w = 0; w < 16; ++w)
      if (w < (tid >> 6)) off += wsum[w];
    lbase[tid] = off + x - v;
    if (tid == NBK - 1) lbase[NBK] = off + x;
    gbase[tid] = v ? atomicAdd(&bucket_cursor[tid], v) : 0;
  }
  __syncthreads();

#pragma unroll
  for (int j = 0; j < 8; ++j)
    if (myb[j] >= 0) sbuf[lbase[myb[j]] + myslot[j]] = mypk[j];
  __syncthreads();

  int total = lbase[NBK];
  int idx = tid * 8;
  if (idx < total) {
    int lo = 0, hi = NBK;
    while (hi - lo > 1) {
      int mid = (lo + hi) >> 1;
      if (lbase[mid] <= idx) lo = mid; else hi = mid;
    }
    int b = lo;
#pragma unroll
    for (int j = 0; j < 8; ++j, ++idx) {
      if (idx >= total) break;
      while (idx >= lbase[b + 1]) ++b;
      pairs[gbase[b] + (idx - lbase[b])] = sbuf[idx];
    }
  }
}

// One block per 128-node bucket; 8 groups of 32 lanes, 8 edges per iteration.
__global__ __launch_bounds__(256) void bucket_agg_kernel(
    const unsigned* __restrict__ pairs, const int* __restrict__ bucket_base,
    const int* __restrict__ bucket_cursor, const float* __restrict__ h,
    const int* __restrict__ cnt_in, const float* __restrict__ bias,
    float* __restrict__ out, int N) {
  __shared__ float acc[BNODES * OUT_F];   // 16 KB, bank = lane
  int tid = threadIdx.x;
  {
    float4 z = {0.f, 0.f, 0.f, 0.f};
    float4* a4 = (float4*)acc;
#pragma unroll
    for (int i = 0; i < 4; ++i) a4[tid + i * 256] = z;
  }
  __syncthreads();

  int b = blockIdx.x;
  int start = bucket_base[b];
  int end = bucket_cursor[b];
  int lane = tid & 31;
  int eg = tid >> 5;   // 8 groups

  for (int p = start + eg * 8; p < end; p += 64) {
    int m = end - p;   // >= 1
    unsigned pk[8];
#pragma unroll
    for (int j = 0; j < 8; ++j) pk[j] = (j < m) ? pairs[p + j] : 0u;
    float f[8];
#pragma unroll
    for (int j = 0; j < 8; ++j) f[j] = h[(size_t)(pk[j] & 0x1FFFF) * OUT_F + lane];
#pragma unroll
    for (int j = 0; j < 8; ++j)
      if (j < m) atomicAdd(&acc[(pk[j] >> 17) * OUT_F + lane], f[j]);
  }
  __syncthreads();

  int node0 = b << BSHIFT;
#pragma unroll
  for (int r = eg; r < BNODES; r += 8) {
    int node = node0 + r;
    if (node < N) {
      float dg = (float)cnt_in[node];
      float sc = dg < 1.f ? 1.f : rsqrtf(dg);
      float v = fmaf(acc[r * OUT_F + lane], sc, bias[lane]);
      out[(size_t)node * OUT_F + lane] = fmaxf(v, 0.f);
    }
  }
}

// ---- fallback (float-atomic) path ----
__global__ __launch_bounds__(256) void aggregate_kernel(
    const int* __restrict__ src, const int* __restrict__ dst,
    const float* __restrict__ h, float* __restrict__ out, int E) {
  int lane = threadIdx.x & 31;
  int e = (blockIdx.x * 256 + threadIdx.x) >> 5;
  if (e >= E) return;
  float v = h[(size_t)src[e] * OUT_F + lane];
  unsafeAtomicAdd(out + (size_t)dst[e] * OUT_F + lane, v);
}

__global__ __launch_bounds__(256) void finalize_kernel(
    float* __restrict__ out, const int* __restrict__ cnt_in,
    const float* __restrict__ bias, int N) {
  int idx = blockIdx.x * 256 + threadIdx.x;
  if (idx >= N * 8) return;
  int n = idx >> 3;
  int o = (idx & 7) * 4;
  float dg = (float)cnt_in[n];
  float s = dg < 1.f ? 1.f : rsqrtf(dg);
  float4 bv = *(const float4*)(bias + o);
  float4 v = ((const float4*)out)[idx];
  v.x = fmaxf(fmaf(v.x, s, bv.x), 0.f);
  v.y = fmaxf(fmaf(v.y, s, bv.y), 0.f);
  v.z = fmaxf(fmaf(v.z, s, bv.z), 0.f);
  v.w = fmaxf(fmaf(v.w, s, bv.w), 0.f);
  ((float4*)out)[idx] = v;
}

extern "C" void kernel_launch(void* const* d_in, const int* in_sizes, int n_in,
                              void* d_out, int out_size, void* d_ws, size_t ws_size,
                              hipStream_t stream) {
  const float* feat = (const float*)d_in[0];
  const int* src = (const int*)d_in[1];
  const int* dst = (const int*)d_in[2];
  const float* weight = (const float*)d_in[3];
  const float* bias = (const float*)d_in[4];
  float* out = (float*)d_out;

  int N = in_sizes[0] / IN_F;
  int E = in_sizes[1];
  int nb = (N + BNODES - 1) >> BSHIFT;

  float* h = (float*)d_ws;                        // N*32 floats
  int* cnt_out = (int*)(h + (size_t)N * OUT_F);   // N
  int* cnt_in = cnt_out + N;                      // N
  int* bucket_cnt = cnt_in + N;                   // NBK
  int* bucket_base = bucket_cnt + NBK;            // NBK+1 (pad)
  int* bucket_cursor = bucket_base + NBK + 1;     // NBK
  unsigned* pairs = (unsigned*)(bucket_cursor + NBK);  // E

  size_t need = ((size_t)N * OUT_F + 2 * (size_t)N + (3 * NBK + 1) + (size_t)E) * 4;
  bool fast = (ws_size >= need) && (N <= (1 << 17)) && (nb <= NBK);

  if (fast) {
    hipMemsetAsync(cnt_out, 0, ((size_t)2 * N + NBK) * sizeof(int), stream);
    degree_kernel<<<(E + DEG_EPB - 1) / DEG_EPB, 256, 0, stream>>>(
        src, dst, cnt_out, cnt_in, bucket_cnt, E);
    gemm_kernel<<<(N + G_ROWS - 1) / G_ROWS, 256, 0, stream>>>(feat, weight, cnt_out, h, N);
    bucket_scan_kernel<<<1, 1024, 0, stream>>>(bucket_cnt, bucket_base, bucket_cursor);
    partition_kernel<<<(E + PB_EDGES - 1) / PB_EDGES, 1024, 0, stream>>>(
        src, dst, bucket_cursor, pairs, E);
    bucket_agg_kernel<<<nb, 256, 0, stream>>>(
        pairs, bucket_base, bucket_cursor, h, cnt_in, bias, out, N);
  } else {
    hipMemsetAsync(cnt_out, 0, (size_t)2 * N * sizeof(int), stream);
    hipMemsetAsync(out, 0, (size_t)N * OUT_F * sizeof(float), stream);
    degree_kernel<<<(E + DEG_EPB - 1) / DEG_EPB, 256, 0, stream>>>(
        src, dst, cnt_out, cnt_in, bucket_cnt, E);
    gemm_kernel<<<(N + G_ROWS - 1) / G_ROWS, 256, 0, stream>>>(feat, weight, cnt_out, h, N);
    aggregate_kernel<<<(E + 7) / 8, 256, 0, stream>>>(src, dst, h, out, E);
    finalize_kernel<<<(N * 8 + 255) / 256, 256, 0, stream>>>(out, cnt_in, bias, N);
  }
}